// Round 7
// baseline (1193.181 us; speedup 1.0000x reference)
//
#include <hip/hip_runtime.h>

// ---------- helpers ----------
typedef __attribute__((ext_vector_type(4))) float f4;
typedef __attribute__((ext_vector_type(8))) short s8;

__device__ inline float b2f(unsigned int u) {
    unsigned int v = u << 16;
    float f;
    __builtin_memcpy(&f, &v, 4);
    return f;
}
__device__ inline unsigned short f2b(float f) {
    unsigned int u;
    __builtin_memcpy(&u, &f, 4);
    unsigned int r = u + 0x7fffu + ((u >> 16) & 1u);
    return (unsigned short)(r >> 16);
}
__device__ inline void async16(const void* g, void* l) {
    __builtin_amdgcn_global_load_lds(
        (const __attribute__((address_space(1))) unsigned int*)g,
        (__attribute__((address_space(3))) unsigned int*)l, 16, 0, 0);
}

#define B_ROWS 8192
#define DIN 1024
#define DH 2048
#define DOUT 1024
#define NE 8
#define NCAT 16384   // NE * DH

#define MFMA16(a, b, c) __builtin_amdgcn_mfma_f32_16x16x32_bf16(a, b, c, 0, 0, 0)

// ---------- dtype detection: flag=1 if inputs are fp32, 0 if bf16 ----------
__global__ __launch_bounds__(64) void detect_dtype(const unsigned short* __restrict__ p, int* __restrict__ flag)
{
    const int lane = threadIdx.x;
    int sane = 0;
    for (int i = lane; i < 4096; i += 64) {
        const float a = fabsf(b2f(p[i]));
        if (a > 1e-30f && a < 1e3f) sane++;
    }
    for (int off = 32; off; off >>= 1) sane += __shfl_xor(sane, off, 64);
    if (lane == 0) *flag = (sane < 3600) ? 1 : 0;
}

// ---------- normalize any input tensor to bf16 ----------
__global__ __launch_bounds__(256) void normalize_kernel(const void* __restrict__ src,
                                                        unsigned short* __restrict__ dst,
                                                        const int* __restrict__ flag, int n)
{
    const int i = blockIdx.x * 256 + threadIdx.x;
    if (i >= n) return;
    if (*flag) dst[i] = f2b(((const float*)src)[i]);
    else       dst[i] = ((const unsigned short*)src)[i];
}

// ---------- gating ----------
__global__ __launch_bounds__(256) void gating_kernel(
    const unsigned short* __restrict__ x, const unsigned short* __restrict__ gum,
    const unsigned short* __restrict__ gw, const unsigned short* __restrict__ gb,
    float* __restrict__ probs, float* __restrict__ partials)
{
    const int t = threadIdx.x, wave = t >> 6, lane = t & 63;
    float sp = 0.f, sr = 0.f;
    const int base = blockIdx.x * 32 + wave * 8;
    for (int rr = 0; rr < 8; rr++) {
        const int b = base + rr;
        float acc[8];
#pragma unroll
        for (int e = 0; e < 8; e++) acc[e] = 0.f;
        for (int kk = 0; kk < 16; kk++) {
            const int k = kk * 64 + lane;
            const float xv = b2f(x[(size_t)b * DIN + k]);
            const uint4 wv = *(const uint4*)(gw + (size_t)k * 8);
            acc[0] += xv * b2f(wv.x & 0xffffu); acc[1] += xv * b2f(wv.x >> 16);
            acc[2] += xv * b2f(wv.y & 0xffffu); acc[3] += xv * b2f(wv.y >> 16);
            acc[4] += xv * b2f(wv.z & 0xffffu); acc[5] += xv * b2f(wv.z >> 16);
            acc[6] += xv * b2f(wv.w & 0xffffu); acc[7] += xv * b2f(wv.w >> 16);
        }
#pragma unroll
        for (int e = 0; e < 8; e++)
            for (int off = 32; off; off >>= 1) acc[e] += __shfl_xor(acc[e], off, 64);
        float lg[8], p1[8], p2[8];
        float m1 = -1e30f, m2 = -1e30f;
#pragma unroll
        for (int e = 0; e < 8; e++) {
            lg[e] = acc[e] + b2f(gb[e]);
            p1[e] = (lg[e] + b2f(gum[(size_t)b * 8 + e])) * 1.25f;  // 1/tau
            p2[e] = lg[e] * 1.25f;
            m1 = fmaxf(m1, p1[e]); m2 = fmaxf(m2, p2[e]);
        }
        float s1 = 0.f, s2 = 0.f;
#pragma unroll
        for (int e = 0; e < 8; e++) {
            p1[e] = expf(p1[e] - m1); s1 += p1[e];
            p2[e] = expf(p2[e] - m2); s2 += p2[e];
        }
        const float i1 = 1.f / s1, i2 = 1.f / s2;
        if (lane < 8) {
            const float pv = p1[lane] * i1;
            probs[(size_t)b * 8 + lane] = pv;
            sp += pv;
            sr += p2[lane] * i2;
        }
    }
    __shared__ float red[4][16];
    if (lane < 8) { red[wave][lane] = sp; red[wave][8 + lane] = sr; }
    __syncthreads();
    if (t < 16)
        partials[blockIdx.x * 16 + t] = red[0][t] + red[1][t] + red[2][t] + red[3][t];
}

// ---------- aux loss finalize (dtype-branched output) ----------
__global__ void aux_finalize(const float* __restrict__ partials, void* __restrict__ outp,
                             const int* __restrict__ flag)
{
    __shared__ float fin[16];
    const int t = threadIdx.x;
    if (t < 16) {
        float s = 0.f;
        for (int i = 0; i < 256; i++) s += partials[i * 16 + t];
        fin[t] = s;
    }
    __syncthreads();
    if (t == 0) {
        float ld[8], im[8];
        for (int e = 0; e < 8; e++) { ld[e] = fin[e] / 8192.f; im[e] = fin[8 + e] / 8192.f; }
        float mi = 0.f, ml = 0.f;
        for (int e = 0; e < 8; e++) { mi += im[e]; ml += ld[e]; }
        mi *= 0.125f; ml *= 0.125f;
        float vi = 0.f, vl = 0.f, sw = 0.f;
        for (int e = 0; e < 8; e++) {
            vi += (im[e] - mi) * (im[e] - mi);
            vl += (ld[e] - ml) * (ld[e] - ml);
            sw += im[e] * ld[e];
        }
        const float cvi = sqrtf(vi / 7.f) / (mi + 1e-8f);
        const float cvl = sqrtf(vl / 7.f) / (ml + 1e-8f);
        const float aux = (8.f * sw + cvi + cvl) * 0.05f;
        if (*flag) ((float*)outp)[8388608] = aux;
        else       ((unsigned short*)outp)[8388608] = f2b(aux);
    }
}

// ---------- batched transpose+cvt: per z: src[z][R][C] -> out[z-block][C][R] ----------
__global__ __launch_bounds__(256) void transpose_cvt(
    const void* __restrict__ src, unsigned short* __restrict__ out,
    int R, int C, int ldOut, size_t outEStride, const int* __restrict__ flag)
{
    __shared__ unsigned short tile[64][65];
    const int e = blockIdx.z;
    const size_t eoff = (size_t)e * R * C;
    unsigned short* op = out + (size_t)e * outEStride;
    const int fl = *flag;
    const int tx = threadIdx.x, ty = threadIdx.y;
    const int r0 = blockIdx.y * 64, c0 = blockIdx.x * 64;
    if (fl) {
        const float* in = (const float*)src + eoff;
#pragma unroll
        for (int i = 0; i < 16; i++) {
            const int r = ty + i * 4;
            tile[r][tx] = f2b(in[(size_t)(r0 + r) * C + c0 + tx]);
        }
    } else {
        const unsigned short* in = (const unsigned short*)src + eoff;
#pragma unroll
        for (int i = 0; i < 16; i++) {
            const int r = ty + i * 4;
            tile[r][tx] = in[(size_t)(r0 + r) * C + c0 + tx];
        }
    }
    __syncthreads();
#pragma unroll
    for (int i = 0; i < 16; i++) {
        const int c = ty + i * 4;
        op[(size_t)(c0 + c) * ldOut + r0 + tx] = tile[tx][c];
    }
}

// =====================================================================
// Per-expert 128x128 GEMM (R1-proven 2-phase dbuf + granule swizzle).
//   EPI 0: H_e[gm][gn] = bf16( relu(x@W1_e + b1_e[gn]) * probs[gm][e] )
//          one launch per expert PAIR: blockIdx.z = 0/1 -> e = eBase+z
//   EPI 1: outacc[gm][gn] += acc + probs[gm][e]*b2_e[gn]  (fp32 RMW;
//          first=1 skips the load)
//   EPI 2: same as 1 but final expert: dtype-branched store to d_out
// probs column e is staged to LDS once per block (e is block-constant:
// n-tiles never straddle an expert boundary).
// LDS tile layout: byte(row,slot)=row*64+slot*16, phys slot =
// logical^( (row>>1)&3 ) — applied on pre-swizzled GLOBAL source
// (global_load_lds writes linearly) and on ds_read offsets (0 conflicts,
// measured R6).
// =====================================================================
template<int K, int LDB, int EPI>
__global__ __launch_bounds__(256) void gemm128(
    const unsigned short* __restrict__ A,
    const unsigned short* __restrict__ BtBase,   // w1Tcat (EPI0) / w2Tcat (EPI1/2)
    const unsigned short* __restrict__ biasBase, // b1n (EPI0) / b2n (EPI1/2)
    const float* __restrict__ probs,
    int eBase,
    unsigned short* __restrict__ outH0,          // EPI0: H pair base
    float* __restrict__ outacc,                  // EPI1/2
    int first,
    void* __restrict__ outp,                     // EPI2
    const int* __restrict__ flag)
{
    __shared__ __align__(16) char smem[32768];   // 2 buffers x (A 8KB + B 8KB)
    __shared__ float probsS[128];

    const int t = threadIdx.x;
    const int ez = (EPI == 0) ? blockIdx.z : 0;
    const int e = eBase + ez;

    // XCD-aware bijective remap over (x,y) (grid.x*grid.y multiple of 8)
    int bid = blockIdx.y * gridDim.x + blockIdx.x;
    const int cpx = (gridDim.x * gridDim.y) >> 3;
    bid = (bid & 7) * cpx + (bid >> 3);
    const int bx = bid % gridDim.x, by = bid / gridDim.x;
    const int m0 = bx * 128, n0 = by * 128;

    const unsigned short* Bt;
    const unsigned short* bias;
    if (EPI == 0) { Bt = BtBase + (size_t)e * DH * DIN; bias = biasBase + e * DH; }
    else          { Bt = BtBase + (size_t)e * DH;       bias = biasBase + e * DOUT; }

    // stage probs column e for this block's 128 rows
    if (t < 128) probsS[t] = probs[(size_t)(m0 + t) * 8 + e];

    const int wave = t >> 6, lane = t & 63;
    const int wm = wave >> 1, wn = wave & 1;
    const int quad = lane >> 4, l16 = lane & 15;

    f4 acc[4][4];
#pragma unroll
    for (int i = 0; i < 4; i++)
#pragma unroll
        for (int j = 0; j < 4; j++) { acc[i][j][0] = 0.f; acc[i][j][1] = 0.f; acc[i][j][2] = 0.f; acc[i][j][3] = 0.f; }

    // staging: lane t -> row t>>2 (per 64-row half), pre-swizzled source granule
    const int rA = t >> 2;
    const int cb = (((t & 3) ^ ((t >> 3) & 3)) * 16);
    const char* pA0 = (const char*)(A + (size_t)(m0 + rA) * K) + cb;
    const char* pA1 = pA0 + (size_t)64 * K * 2;
    const char* pB0 = (const char*)(Bt + (size_t)(n0 + rA) * LDB) + cb;
    const char* pB1 = pB0 + (size_t)64 * LDB * 2;

    // read offsets: byte = row*64 + ((quad ^ ((l16>>1)&3))*16)
    const int skey = ((quad ^ ((l16 >> 1) & 3)) << 4);
    int aoff[4], boff[4];
#pragma unroll
    for (int i = 0; i < 4; i++) {
        aoff[i] = (wm * 64 + i * 16 + l16) * 64 + skey;
        boff[i] = (wn * 64 + i * 16 + l16) * 64 + skey;
    }

    // prologue
    {
        char* s = smem;
        async16(pA0, s + t * 16);
        async16(pA1, s + 4096 + t * 16);
        async16(pB0, s + 8192 + t * 16);
        async16(pB1, s + 12288 + t * 16);
    }
    __syncthreads();

    int cur = 0;
    for (int k0 = 0; k0 < K; k0 += 32) {
        if (k0 + 32 < K) {
            char* s = smem + (cur ^ 1) * 16384;
            const size_t kb = (size_t)(k0 + 32) * 2;
            async16(pA0 + kb, s + t * 16);
            async16(pA1 + kb, s + 4096 + t * 16);
            async16(pB0 + kb, s + 8192 + t * 16);
            async16(pB1 + kb, s + 12288 + t * 16);
        }
        const char* s = smem + cur * 16384;
        s8 av[4], bv[4];
#pragma unroll
        for (int i = 0; i < 4; i++) av[i] = *(const s8*)(s + aoff[i]);
#pragma unroll
        for (int j = 0; j < 4; j++) bv[j] = *(const s8*)(s + 8192 + boff[j]);
#pragma unroll
        for (int i = 0; i < 4; i++)
#pragma unroll
            for (int j = 0; j < 4; j++)
                acc[i][j] = MFMA16(av[i], bv[j], acc[i][j]);
        __syncthreads();
        cur ^= 1;
    }

    if (EPI == 0) {
        unsigned short* outH = outH0 + (size_t)ez * B_ROWS * DH;
#pragma unroll
        for (int j = 0; j < 4; j++) {
            const int gn = n0 + wn * 64 + j * 16 + l16;
            const float bval = b2f(bias[gn]);
#pragma unroll
            for (int i = 0; i < 4; i++) {
                const int lmB = wm * 64 + i * 16 + quad * 4;
#pragma unroll
                for (int r = 0; r < 4; r++) {
                    const int lm = lmB + r;
                    const float v = fmaxf(acc[i][j][r] + bval, 0.f) * probsS[lm];
                    outH[(size_t)(m0 + lm) * DH + gn] = f2b(v);
                }
            }
        }
    } else {
        const int fl = (EPI == 2) ? *flag : 0;
#pragma unroll
        for (int j = 0; j < 4; j++) {
            const int gn = n0 + wn * 64 + j * 16 + l16;
            const float b2v = b2f(bias[gn]);
#pragma unroll
            for (int i = 0; i < 4; i++) {
                const int lmB = wm * 64 + i * 16 + quad * 4;
#pragma unroll
                for (int r = 0; r < 4; r++) {
                    const int lm = lmB + r;
                    const size_t idx = (size_t)(m0 + lm) * DOUT + gn;
                    float v = acc[i][j][r] + probsS[lm] * b2v;
                    if (!first) v += outacc[idx];
                    if (EPI == 1) {
                        outacc[idx] = v;
                    } else {
                        if (fl) ((float*)outp)[idx] = v;
                        else    ((unsigned short*)outp)[idx] = f2b(v);
                    }
                }
            }
        }
    }
}

extern "C" void kernel_launch(void* const* d_in, const int* in_sizes, int n_in,
                              void* d_out, int out_size, void* d_ws, size_t ws_size,
                              hipStream_t stream)
{
    const void* x   = d_in[0];
    const void* gum = d_in[1];
    const void* gw  = d_in[2];
    const void* gb  = d_in[3];
    const void* w1  = d_in[4];
    const void* b1  = d_in[5];
    const void* w2  = d_in[6];
    const void* b2  = d_in[7];

    char* ws = (char*)d_ws;
    size_t cur = 0;
    auto alloc = [&](size_t bytes) { size_t p = cur; cur = (cur + bytes + 255) & ~(size_t)255; return p; };

    int* flag              = (int*)(ws + alloc(256));
    float* probs           = (float*)(ws + alloc(8192 * 8 * 4));
    float* partials        = (float*)(ws + alloc(256 * 16 * 4));
    unsigned short* xn     = (unsigned short*)(ws + alloc((size_t)B_ROWS * DIN * 2));
    unsigned short* gumn   = (unsigned short*)(ws + alloc((size_t)B_ROWS * 8 * 2));
    unsigned short* gwn    = (unsigned short*)(ws + alloc((size_t)DIN * 8 * 2));
    unsigned short* gbn    = (unsigned short*)(ws + alloc(8 * 2));
    unsigned short* b1n    = (unsigned short*)(ws + alloc((size_t)NE * DH * 2));
    unsigned short* b2n    = (unsigned short*)(ws + alloc((size_t)NE * DOUT * 2));
    unsigned short* w1Tcat = (unsigned short*)(ws + alloc((size_t)NCAT * DIN * 2));   // 32 MiB
    unsigned short* w2Tcat = (unsigned short*)(ws + alloc((size_t)DOUT * NCAT * 2));  // 32 MiB
    unsigned short* Hpair  = (unsigned short*)(ws + alloc((size_t)2 * B_ROWS * DH * 2)); // 64 MiB
    float* outacc          = (float*)(ws + alloc((size_t)B_ROWS * DOUT * 4));            // 32 MiB
    (void)cur;  // ~177 MB total

    detect_dtype<<<1, 64, 0, stream>>>((const unsigned short*)x, flag);

    normalize_kernel<<<(B_ROWS * DIN + 255) / 256, 256, 0, stream>>>(x, xn, flag, B_ROWS * DIN);
    normalize_kernel<<<(B_ROWS * 8 + 255) / 256, 256, 0, stream>>>(gum, gumn, flag, B_ROWS * 8);
    normalize_kernel<<<(DIN * 8 + 255) / 256, 256, 0, stream>>>(gw, gwn, flag, DIN * 8);
    normalize_kernel<<<1, 256, 0, stream>>>(gb, gbn, flag, 8);
    normalize_kernel<<<(NE * DH + 255) / 256, 256, 0, stream>>>(b1, b1n, flag, NE * DH);
    normalize_kernel<<<(NE * DOUT + 255) / 256, 256, 0, stream>>>(b2, b2n, flag, NE * DOUT);

    gating_kernel<<<256, 256, 0, stream>>>(xn, gumn, gwn, gbn, probs, partials);
    aux_finalize<<<1, 64, 0, stream>>>(partials, d_out, flag);

    transpose_cvt<<<dim3(DH / 64, DIN / 64, NE), dim3(64, 4), 0, stream>>>(
        w1, w1Tcat, DIN, DH, DIN, (size_t)DH * DIN, flag);
    transpose_cvt<<<dim3(DOUT / 64, DH / 64, NE), dim3(64, 4), 0, stream>>>(
        w2, w2Tcat, DH, DOUT, NCAT, (size_t)DH, flag);

    // per expert-pair: gemm1 for (e, e+1) in one 2048-block launch,
    // then two 512-block gemm2 RMW launches (last one writes d_out).
    for (int p = 0; p < 4; p++) {
        const int e0 = 2 * p;
        gemm128<DIN, DIN, 0><<<dim3(B_ROWS / 128, DH / 128, 2), 256, 0, stream>>>(
            xn, w1Tcat, b1n, probs, e0, Hpair, nullptr, 0, nullptr, nullptr);
        for (int z = 0; z < 2; z++) {
            const int e = e0 + z;
            const unsigned short* He = Hpair + (size_t)z * B_ROWS * DH;
            if (e < NE - 1)
                gemm128<DH, NCAT, 1><<<dim3(B_ROWS / 128, DOUT / 128), 256, 0, stream>>>(
                    He, w2Tcat, b2n, probs, e, nullptr, outacc, e == 0, nullptr, nullptr);
            else
                gemm128<DH, NCAT, 2><<<dim3(B_ROWS / 128, DOUT / 128), 256, 0, stream>>>(
                    He, w2Tcat, b2n, probs, e, nullptr, outacc, 0, d_out, flag);
        }
    }
}

// Round 8
// 971.404 us; speedup vs baseline: 1.2283x; 1.2283x over previous
//
#include <hip/hip_runtime.h>

// ---------- helpers ----------
typedef __attribute__((ext_vector_type(4))) float f4;
typedef __attribute__((ext_vector_type(8))) short s8;
typedef __attribute__((ext_vector_type(4))) unsigned short us4;

__device__ inline float b2f(unsigned int u) {
    unsigned int v = u << 16;
    float f;
    __builtin_memcpy(&f, &v, 4);
    return f;
}
__device__ inline unsigned short f2b(float f) {
    unsigned int u;
    __builtin_memcpy(&u, &f, 4);
    unsigned int r = u + 0x7fffu + ((u >> 16) & 1u);
    return (unsigned short)(r >> 16);
}
__device__ inline void async16(const void* g, void* l) {
    __builtin_amdgcn_global_load_lds(
        (const __attribute__((address_space(1))) unsigned int*)g,
        (__attribute__((address_space(3))) unsigned int*)l, 16, 0, 0);
}

#define B_ROWS 8192
#define DIN 1024
#define DH 2048
#define DOUT 1024
#define NE 8
#define NCAT 16384   // NE * DH

#define MFMA16(a, b, c) __builtin_amdgcn_mfma_f32_16x16x32_bf16(a, b, c, 0, 0, 0)

// ---------- dtype detection: flag=1 if inputs are fp32, 0 if bf16 ----------
__global__ __launch_bounds__(64) void detect_dtype(const unsigned short* __restrict__ p, int* __restrict__ flag)
{
    const int lane = threadIdx.x;
    int sane = 0;
    for (int i = lane; i < 4096; i += 64) {
        const float a = fabsf(b2f(p[i]));
        if (a > 1e-30f && a < 1e3f) sane++;
    }
    for (int off = 32; off; off >>= 1) sane += __shfl_xor(sane, off, 64);
    if (lane == 0) *flag = (sane < 3600) ? 1 : 0;
}

// ---------- normalize any input tensor to bf16 ----------
__global__ __launch_bounds__(256) void normalize_kernel(const void* __restrict__ src,
                                                        unsigned short* __restrict__ dst,
                                                        const int* __restrict__ flag, int n)
{
    const int i = blockIdx.x * 256 + threadIdx.x;
    if (i >= n) return;
    if (*flag) dst[i] = f2b(((const float*)src)[i]);
    else       dst[i] = ((const unsigned short*)src)[i];
}

// ---------- gating ----------
__global__ __launch_bounds__(256) void gating_kernel(
    const unsigned short* __restrict__ x, const unsigned short* __restrict__ gum,
    const unsigned short* __restrict__ gw, const unsigned short* __restrict__ gb,
    float* __restrict__ probs, float* __restrict__ partials)
{
    const int t = threadIdx.x, wave = t >> 6, lane = t & 63;
    float sp = 0.f, sr = 0.f;
    const int base = blockIdx.x * 32 + wave * 8;
    for (int rr = 0; rr < 8; rr++) {
        const int b = base + rr;
        float acc[8];
#pragma unroll
        for (int e = 0; e < 8; e++) acc[e] = 0.f;
        for (int kk = 0; kk < 16; kk++) {
            const int k = kk * 64 + lane;
            const float xv = b2f(x[(size_t)b * DIN + k]);
            const uint4 wv = *(const uint4*)(gw + (size_t)k * 8);
            acc[0] += xv * b2f(wv.x & 0xffffu); acc[1] += xv * b2f(wv.x >> 16);
            acc[2] += xv * b2f(wv.y & 0xffffu); acc[3] += xv * b2f(wv.y >> 16);
            acc[4] += xv * b2f(wv.z & 0xffffu); acc[5] += xv * b2f(wv.z >> 16);
            acc[6] += xv * b2f(wv.w & 0xffffu); acc[7] += xv * b2f(wv.w >> 16);
        }
#pragma unroll
        for (int e = 0; e < 8; e++)
            for (int off = 32; off; off >>= 1) acc[e] += __shfl_xor(acc[e], off, 64);
        float lg[8], p1[8], p2[8];
        float m1 = -1e30f, m2 = -1e30f;
#pragma unroll
        for (int e = 0; e < 8; e++) {
            lg[e] = acc[e] + b2f(gb[e]);
            p1[e] = (lg[e] + b2f(gum[(size_t)b * 8 + e])) * 1.25f;  // 1/tau
            p2[e] = lg[e] * 1.25f;
            m1 = fmaxf(m1, p1[e]); m2 = fmaxf(m2, p2[e]);
        }
        float s1 = 0.f, s2 = 0.f;
#pragma unroll
        for (int e = 0; e < 8; e++) {
            p1[e] = expf(p1[e] - m1); s1 += p1[e];
            p2[e] = expf(p2[e] - m2); s2 += p2[e];
        }
        const float i1 = 1.f / s1, i2 = 1.f / s2;
        if (lane < 8) {
            const float pv = p1[lane] * i1;
            probs[(size_t)b * 8 + lane] = pv;
            sp += pv;
            sr += p2[lane] * i2;
        }
    }
    __shared__ float red[4][16];
    if (lane < 8) { red[wave][lane] = sp; red[wave][8 + lane] = sr; }
    __syncthreads();
    if (t < 16)
        partials[blockIdx.x * 16 + t] = red[0][t] + red[1][t] + red[2][t] + red[3][t];
}

// ---------- aux loss finalize (dtype-branched output) ----------
__global__ void aux_finalize(const float* __restrict__ partials, void* __restrict__ outp,
                             const int* __restrict__ flag)
{
    __shared__ float fin[16];
    const int t = threadIdx.x;
    if (t < 16) {
        float s = 0.f;
        for (int i = 0; i < 256; i++) s += partials[i * 16 + t];
        fin[t] = s;
    }
    __syncthreads();
    if (t == 0) {
        float ld[8], im[8];
        for (int e = 0; e < 8; e++) { ld[e] = fin[e] / 8192.f; im[e] = fin[8 + e] / 8192.f; }
        float mi = 0.f, ml = 0.f;
        for (int e = 0; e < 8; e++) { mi += im[e]; ml += ld[e]; }
        mi *= 0.125f; ml *= 0.125f;
        float vi = 0.f, vl = 0.f, sw = 0.f;
        for (int e = 0; e < 8; e++) {
            vi += (im[e] - mi) * (im[e] - mi);
            vl += (ld[e] - ml) * (ld[e] - ml);
            sw += im[e] * ld[e];
        }
        const float cvi = sqrtf(vi / 7.f) / (mi + 1e-8f);
        const float cvl = sqrtf(vl / 7.f) / (ml + 1e-8f);
        const float aux = (8.f * sw + cvi + cvl) * 0.05f;
        if (*flag) ((float*)outp)[8388608] = aux;
        else       ((unsigned short*)outp)[8388608] = f2b(aux);
    }
}

// ---------- batched transpose+cvt: per z: src[z][R][C] -> out[z-block][C][R] ----------
__global__ __launch_bounds__(256) void transpose_cvt(
    const void* __restrict__ src, unsigned short* __restrict__ out,
    int R, int C, int ldOut, size_t outEStride, const int* __restrict__ flag)
{
    __shared__ unsigned short tile[64][65];
    const int e = blockIdx.z;
    const size_t eoff = (size_t)e * R * C;
    unsigned short* op = out + (size_t)e * outEStride;
    const int fl = *flag;
    const int tx = threadIdx.x, ty = threadIdx.y;
    const int r0 = blockIdx.y * 64, c0 = blockIdx.x * 64;
    if (fl) {
        const float* in = (const float*)src + eoff;
#pragma unroll
        for (int i = 0; i < 16; i++) {
            const int r = ty + i * 4;
            tile[r][tx] = f2b(in[(size_t)(r0 + r) * C + c0 + tx]);
        }
    } else {
        const unsigned short* in = (const unsigned short*)src + eoff;
#pragma unroll
        for (int i = 0; i < 16; i++) {
            const int r = ty + i * 4;
            tile[r][tx] = in[(size_t)(r0 + r) * C + c0 + tx];
        }
    }
    __syncthreads();
#pragma unroll
    for (int i = 0; i < 16; i++) {
        const int c = ty + i * 4;
        op[(size_t)(c0 + c) * ldOut + r0 + tx] = tile[tx][c];
    }
}

// =====================================================================
// Granule swizzle (both GEMMs), measured conflict-free in R6:
//   LDS tile layout: byte(row, slot) = row*64 + slot*16,
//   phys slot = logical_granule ^ ((row>>1)&3).
//   global_load_lds writes linearly -> swizzle applied on GLOBAL source
//   column; ds_read offsets apply the same key.
// =====================================================================

// ---------- GEMM1: 128x128 2-phase dbuf + swizzle + XCD remap ----------
// Hcat[m,n] = bf16( relu(x@W1cat + b1cat[n]) * probs[m, n>>11] ), K=1024
// __launch_bounds__(256, 4): cap 128 unified regs/wave -> 4 blocks/CU.
// Budget: acc 64 AGPR + frags 32 VGPR + addr ~25 ~= 121 <= 128 (no spill
// expected; tripwire = VGPR_Count 64 AND WRITE_SIZE blowup).
__global__ __launch_bounds__(256, 4) void gemm_h(
    const unsigned short* __restrict__ A,
    const unsigned short* __restrict__ Bt,
    const unsigned short* __restrict__ bias,
    const float* __restrict__ probs,
    unsigned short* __restrict__ outH)
{
    constexpr int K = DIN;
    __shared__ __align__(16) char smem[32768];   // 2 buffers x (A 8KB + B 8KB)
    __shared__ float probsS[128];

    const int t = threadIdx.x;
    // XCD-aware bijective remap (grid is a multiple of 8 blocks)
    int bid = blockIdx.y * gridDim.x + blockIdx.x;
    const int cpx = (gridDim.x * gridDim.y) >> 3;
    bid = (bid & 7) * cpx + (bid >> 3);
    const int bx = bid % gridDim.x, by = bid / gridDim.x;
    const int m0 = bx * 128, n0 = by * 128;

    // n-tile lies entirely within one expert (2048 % 128 == 0)
    if (t < 128) probsS[t] = probs[(size_t)(m0 + t) * 8 + (n0 >> 11)];

    const int wave = t >> 6, lane = t & 63;
    const int wm = wave >> 1, wn = wave & 1;
    const int quad = lane >> 4, l16 = lane & 15;

    f4 acc[4][4];
#pragma unroll
    for (int i = 0; i < 4; i++)
#pragma unroll
        for (int j = 0; j < 4; j++) { acc[i][j][0] = 0.f; acc[i][j][1] = 0.f; acc[i][j][2] = 0.f; acc[i][j][3] = 0.f; }

    // staging: lane t -> row t>>2 (per 64-row half), phys slot t&3,
    // pre-swizzled source granule (t&3)^((t>>3)&3)
    const int rA = t >> 2;
    const int cb = (((t & 3) ^ ((t >> 3) & 3)) * 16);
    const char* pA0 = (const char*)(A + (size_t)(m0 + rA) * K) + cb;
    const char* pA1 = pA0 + (size_t)64 * K * 2;
    const char* pB0 = (const char*)(Bt + (size_t)(n0 + rA) * K) + cb;
    const char* pB1 = pB0 + (size_t)64 * K * 2;

    // read offsets: byte = row*64 + ((quad ^ ((l16>>1)&3))*16)
    const int skey = ((quad ^ ((l16 >> 1) & 3)) << 4);
    int aoff[4], boff[4];
#pragma unroll
    for (int i = 0; i < 4; i++) {
        aoff[i] = (wm * 64 + i * 16 + l16) * 64 + skey;
        boff[i] = (wn * 64 + i * 16 + l16) * 64 + skey;
    }

    // prologue
    {
        char* s = smem;
        async16(pA0, s + t * 16);
        async16(pA1, s + 4096 + t * 16);
        async16(pB0, s + 8192 + t * 16);
        async16(pB1, s + 12288 + t * 16);
    }
    __syncthreads();

    int cur = 0;
    for (int k0 = 0; k0 < K; k0 += 32) {
        if (k0 + 32 < K) {
            char* s = smem + (cur ^ 1) * 16384;
            const size_t kb = (size_t)(k0 + 32) * 2;
            async16(pA0 + kb, s + t * 16);
            async16(pA1 + kb, s + 4096 + t * 16);
            async16(pB0 + kb, s + 8192 + t * 16);
            async16(pB1 + kb, s + 12288 + t * 16);
        }
        const char* s = smem + cur * 16384;
        s8 av[4], bv[4];
#pragma unroll
        for (int i = 0; i < 4; i++) av[i] = *(const s8*)(s + aoff[i]);
#pragma unroll
        for (int j = 0; j < 4; j++) bv[j] = *(const s8*)(s + 8192 + boff[j]);
#pragma unroll
        for (int i = 0; i < 4; i++)
#pragma unroll
            for (int j = 0; j < 4; j++)
                acc[i][j] = MFMA16(av[i], bv[j], acc[i][j]);
        __syncthreads();
        cur ^= 1;
    }

#pragma unroll
    for (int i = 0; i < 4; i++) {
        const int lmB = wm * 64 + i * 16 + quad * 4;
#pragma unroll
        for (int j = 0; j < 4; j++) {
            const int gn = n0 + wn * 64 + j * 16 + l16;
            const float bval = b2f(bias[gn]);
#pragma unroll
            for (int r = 0; r < 4; r++) {
                const int lm = lmB + r;
                float v = acc[i][j][r] + bval;
                v = fmaxf(v, 0.f) * probsS[lm];
                outH[(size_t)(m0 + lm) * NCAT + gn] = f2b(v);
            }
        }
    }
}

// ---------- GEMM2 (split-K): 128M x 256N, 8 waves (2Mx4N) — unchanged R6 control ----------
__global__ __launch_bounds__(512, 4) void gemm_o3(
    const unsigned short* __restrict__ A,    // Hcat [rows][16384]
    const unsigned short* __restrict__ Bt,   // w2Tcat [1024][16384]
    float* __restrict__ partial, int rows, int klen)
{
    constexpr int K = NCAT;
    __shared__ __align__(16) char smem[49152];   // 2 x (A 8KB + B 16KB)
    const int t = threadIdx.x;
    const int w = t >> 6, l = t & 63;
    const int l15 = l & 15, q = l >> 4;
    const int wm = w >> 2, wn = w & 3;

    const int m0 = blockIdx.x * 128, n0 = blockIdx.y * 256;
    const int kstart = blockIdx.z * klen;

    // staging: wave w covers A rows [w*16,+16) (1 instr), B rows [w*32,+32) (2 instr)
    const int srow = l >> 2;
    const int gr = ((l & 3) ^ ((l >> 3) & 3)) * 8;   // pre-swizzled source col (elements)
    const unsigned short* pa  = A  + (size_t)(m0 + w * 16 + srow) * K + kstart + gr;
    const unsigned short* pb0 = Bt + (size_t)(n0 + w * 32 + srow) * K + kstart + gr;
    const unsigned short* pb1 = pb0 + (size_t)16 * K;

    const int skey = ((q ^ ((l15 >> 1) & 3)) << 4);
    int aoff[4], boff[4];
#pragma unroll
    for (int mf = 0; mf < 4; mf++) aoff[mf] = (wm * 64 + mf * 16 + l15) * 64 + skey;
#pragma unroll
    for (int nf = 0; nf < 4; nf++) boff[nf] = (wn * 64 + nf * 16 + l15) * 64 + skey;

    f4 acc[4][4];
#pragma unroll
    for (int i = 0; i < 4; i++)
#pragma unroll
        for (int j = 0; j < 4; j++) { acc[i][j][0] = 0.f; acc[i][j][1] = 0.f; acc[i][j][2] = 0.f; acc[i][j][3] = 0.f; }

    // prologue
    {
        char* Ab = smem; char* Bb = smem + 8192;
        async16(pa,  Ab + w * 1024 + (l & 63) * 16);
        async16(pb0, Bb + w * 2048 + (l & 63) * 16);
        async16(pb1, Bb + w * 2048 + 1024 + (l & 63) * 16);
    }
    __syncthreads();

    int cur = 0;
    for (int k0 = 0; k0 < klen; k0 += 32) {
        if (k0 + 32 < klen) {
            char* Ab = smem + (cur ^ 1) * 24576; char* Bb = Ab + 8192;
            const int kn = k0 + 32;
            async16(pa + kn,  Ab + w * 1024 + (l & 63) * 16);
            async16(pb0 + kn, Bb + w * 2048 + (l & 63) * 16);
            async16(pb1 + kn, Bb + w * 2048 + 1024 + (l & 63) * 16);
        }
        const char* Ab = smem + cur * 24576;
        const char* Bb = Ab + 8192;
        s8 Af[4], Bf[4];
#pragma unroll
        for (int mf = 0; mf < 4; mf++) Af[mf] = *(const s8*)(Ab + aoff[mf]);
#pragma unroll
        for (int nf = 0; nf < 4; nf++) Bf[nf] = *(const s8*)(Bb + boff[nf]);
#pragma unroll
        for (int mf = 0; mf < 4; mf++)
#pragma unroll
            for (int nf = 0; nf < 4; nf++)
                acc[mf][nf] = MFMA16(Af[mf], Bf[nf], acc[mf][nf]);
        __syncthreads();
        cur ^= 1;
    }

    float* pp = partial + (size_t)blockIdx.z * rows * DOUT;
#pragma unroll
    for (int mf = 0; mf < 4; mf++) {
        const int gmB = m0 + wm * 64 + mf * 16 + q * 4;
#pragma unroll
        for (int nf = 0; nf < 4; nf++) {
            const int gn = n0 + wn * 64 + nf * 16 + l15;
#pragma unroll
            for (int r = 0; r < 4; r++)
                pp[(size_t)(gmB + r) * DOUT + gn] = acc[mf][nf][r];
        }
    }
}

// ---------- out finalize (vec4): sum split-K partials + probs.b2 bias ----------
__global__ __launch_bounds__(256) void out_finalize(
    const float* __restrict__ partial, const unsigned short* __restrict__ b2,
    const float* __restrict__ probs, void* __restrict__ outp, size_t outOff,
    const int* __restrict__ flag, int rows, int nks)
{
    const int i4 = (blockIdx.x * 256 + threadIdx.x) * 4;
    if (i4 >= rows * DOUT) return;
    const int m = i4 >> 10, n = i4 & (DOUT - 1);
    f4 v = *(const f4*)(partial + i4);
    for (int ks = 1; ks < nks; ks++) {
        const f4 pv = *(const f4*)(partial + (size_t)ks * rows * DOUT + i4);
        v[0] += pv[0]; v[1] += pv[1]; v[2] += pv[2]; v[3] += pv[3];
    }
    const f4 p0 = *(const f4*)(probs + (size_t)m * 8);
    const f4 p1 = *(const f4*)(probs + (size_t)m * 8 + 4);
#pragma unroll
    for (int e = 0; e < 8; e++) {
        const us4 bv = *(const us4*)(b2 + e * DOUT + n);
        const float pe = (e < 4) ? p0[e] : p1[e - 4];
        v[0] += pe * b2f(bv[0]); v[1] += pe * b2f(bv[1]);
        v[2] += pe * b2f(bv[2]); v[3] += pe * b2f(bv[3]);
    }
    const size_t oi = outOff + i4;
    if (*flag) {
        *(f4*)((float*)outp + oi) = v;
    } else {
        us4 o;
        o[0] = f2b(v[0]); o[1] = f2b(v[1]); o[2] = f2b(v[2]); o[3] = f2b(v[3]);
        *(us4*)((unsigned short*)outp + oi) = o;
    }
}

extern "C" void kernel_launch(void* const* d_in, const int* in_sizes, int n_in,
                              void* d_out, int out_size, void* d_ws, size_t ws_size,
                              hipStream_t stream)
{
    const void* x   = d_in[0];
    const void* gum = d_in[1];
    const void* gw  = d_in[2];
    const void* gb  = d_in[3];
    const void* w1  = d_in[4];
    const void* b1  = d_in[5];
    const void* w2  = d_in[6];
    const void* b2  = d_in[7];

    char* ws = (char*)d_ws;
    size_t cur = 0;
    auto alloc = [&](size_t bytes) { size_t p = cur; cur = (cur + bytes + 255) & ~(size_t)255; return p; };

    int* flag              = (int*)(ws + alloc(256));
    float* probs           = (float*)(ws + alloc(8192 * 8 * 4));
    float* partials        = (float*)(ws + alloc(256 * 16 * 4));
    unsigned short* xn     = (unsigned short*)(ws + alloc((size_t)B_ROWS * DIN * 2));
    unsigned short* gumn   = (unsigned short*)(ws + alloc((size_t)B_ROWS * 8 * 2));
    unsigned short* gwn    = (unsigned short*)(ws + alloc((size_t)DIN * 8 * 2));
    unsigned short* gbn    = (unsigned short*)(ws + alloc(8 * 2));
    unsigned short* b1n    = (unsigned short*)(ws + alloc((size_t)NE * DH * 2));
    unsigned short* b2n    = (unsigned short*)(ws + alloc((size_t)NE * DOUT * 2));
    unsigned short* w1Tcat = (unsigned short*)(ws + alloc((size_t)NCAT * DIN * 2));   // 32 MiB
    unsigned short* w2Tcat = (unsigned short*)(ws + alloc((size_t)DOUT * NCAT * 2));  // 32 MiB
    const size_t fixed = cur;  // ~81 MB

    // Chunk sizing. Invariant KS*R == 16384:
    //   partial buffer = 64 MB constant;
    //   gemm_o3 grid = (R/128) * (1024/256) * KS = 512 blocks for any R.
    int R = B_ROWS, KS;
    for (;;) {
        KS = 16384 / R;
        const size_t need = fixed + (size_t)R * (NCAT * 2) + (size_t)KS * R * DOUT * 4;
        if (R <= 512 || need <= ws_size) break;
        R >>= 1;
    }
    const int klen = 16384 / KS;   // multiple of 32
    unsigned short* Hcat = (unsigned short*)(ws + fixed);
    float* partial = (float*)(ws + fixed + (size_t)R * (NCAT * 2));

    detect_dtype<<<1, 64, 0, stream>>>((const unsigned short*)x, flag);

    normalize_kernel<<<(B_ROWS * DIN + 255) / 256, 256, 0, stream>>>(x, xn, flag, B_ROWS * DIN);
    normalize_kernel<<<(B_ROWS * 8 + 255) / 256, 256, 0, stream>>>(gum, gumn, flag, B_ROWS * 8);
    normalize_kernel<<<(DIN * 8 + 255) / 256, 256, 0, stream>>>(gw, gwn, flag, DIN * 8);
    normalize_kernel<<<1, 256, 0, stream>>>(gb, gbn, flag, 8);
    normalize_kernel<<<(NE * DH + 255) / 256, 256, 0, stream>>>(b1, b1n, flag, NE * DH);
    normalize_kernel<<<(NE * DOUT + 255) / 256, 256, 0, stream>>>(b2, b2n, flag, NE * DOUT);

    gating_kernel<<<256, 256, 0, stream>>>(xn, gumn, gwn, gbn, probs, partials);
    aux_finalize<<<1, 64, 0, stream>>>(partials, d_out, flag);

    transpose_cvt<<<dim3(DH / 64, DIN / 64, NE), dim3(64, 4), 0, stream>>>(
        w1, w1Tcat, DIN, DH, DIN, (size_t)DH * DIN, flag);
    transpose_cvt<<<dim3(DOUT / 64, DH / 64, NE), dim3(64, 4), 0, stream>>>(
        w2, w2Tcat, DH, DOUT, NCAT, (size_t)DH, flag);

    for (int c0 = 0; c0 < B_ROWS; c0 += R) {
        gemm_h<<<dim3(R / 128, NCAT / 128), 256, 0, stream>>>(
            xn + (size_t)c0 * DIN, w1Tcat, b1n, probs + (size_t)c0 * 8, Hcat);
        gemm_o3<<<dim3(R / 128, DOUT / 256, KS), 512, 0, stream>>>(
            Hcat, w2Tcat, partial, R, klen);
        out_finalize<<<(R * DOUT / 4 + 255) / 256, 256, 0, stream>>>(
            partial, b2n, probs + (size_t)c0 * 8, d_out, (size_t)c0 * DOUT, flag, R, KS);
    }
}